// Round 4
// baseline (353.488 us; speedup 1.0000x reference)
//
#include <hip/hip_runtime.h>

// GCN layer: out = relu(segment_sum(features[edge_src], edge_dst) @ W + b)
// N=100000, E=1600000, D=F=128.
//
// Structure:
//  1) fill: bucket edges into (dst-block, dst&7) sub-buckets. Counters are
//     padded to ONE PER 64B LINE (round-3 post-mortem: 16 counters/line gave
//     ~2048 serialized same-line atomics -> ~160us; padding -> 128/line).
//     Entries packed src|(dl<<17) into 4B.
//  2) fused: per block of 64 dst rows, 8 groups of 32 lanes; group g owns
//     sub-bucket g (rows dl%8==g -> race-free LDS accumulation). 16-deep
//     gather batches + next-window entry prefetch, then register-tiled
//     GEMM+bias+relu.

constexpr int D     = 128;  // input feature dim
constexpr int F     = 128;  // output feature dim
constexpr int SCAP  = 256;  // per-sub-bucket capacity (Poisson(128): P(>256)~0)
constexpr int CPAD  = 16;   // counter stride in ints (64B line-exclusive)

// ---------------------------------------------------------------------------
// Kernel 1: bucket edges. sub = (dst>>6)*8 + (dst&7); entry = src | (dl<<17).
// Requires N < 2^17 (N=100000 ok).
// ---------------------------------------------------------------------------
__global__ __launch_bounds__(256) void fill_kernel(
    const int* __restrict__ src,
    const int* __restrict__ dst,
    int* __restrict__ bcnt,
    int* __restrict__ bslot,
    int E) {
  int e = blockIdx.x * 256 + threadIdx.x;
  if (e >= E) return;
  int t = dst[e];
  int s = src[e];
  int dl = t & 63;
  int sub = (t >> 6) * 8 + (dl & 7);
  int pos = atomicAdd(&bcnt[sub * CPAD], 1);
  if (pos < SCAP) bslot[(size_t)sub * SCAP + pos] = s | (dl << 17);
}

// ---------------------------------------------------------------------------
// Kernel 2 (fused): aggregate 64 rows into LDS, then GEMM+bias+relu.
// ---------------------------------------------------------------------------
__global__ __launch_bounds__(256) void fused_kernel(
    const float* __restrict__ feat,
    const int* __restrict__ bcnt,
    const int* __restrict__ bslot,
    const float* __restrict__ W,
    const float* __restrict__ b,
    float* __restrict__ out,
    int N) {
  __shared__ float hl[64 * D];  // 32 KB

  int row0 = blockIdx.x * 64;
  int l = threadIdx.x & 31;   // lane within group
  int g = threadIdx.x >> 5;   // group 0..7 owns rows dl%8==g

  const float4* feat4 = (const float4*)feat;
  float4* hl4 = (float4*)hl;

  // ---- Phase 1: zero my rows, then accumulate my sub-bucket ----
  float4 z4 = make_float4(0.f, 0.f, 0.f, 0.f);
#pragma unroll
  for (int r = 0; r < 8; ++r) hl4[(8 * r + g) * 32 + l] = z4;

  int sub = blockIdx.x * 8 + g;
  int c = min(bcnt[sub * CPAD], SCAP);
  const int* sl = bslot + (size_t)sub * SCAP;

  // Entry window prefetch: 32 entries in regs, coalesced load.
  int ent = (l < c) ? sl[l] : 0;

  int nfull = c >> 5;   // number of full 32-entry windows
  for (int w = 0; w < nfull; ++w) {
    int base = w * 32;
    // prefetch next window while this one is processed
    int ent_next = (base + 32 + l < c) ? sl[base + 32 + l] : 0;
#pragma unroll
    for (int half = 0; half < 2; ++half) {
      // 16 independent 512B gathers in flight, then ordered LDS rmw
      float4 v[16];
      int dl16[16];
#pragma unroll
      for (int k = 0; k < 16; ++k) {
        int e = __shfl(ent, half * 16 + k, 32);
        v[k] = feat4[(size_t)(e & 0x1FFFF) * 32 + l];
        dl16[k] = e >> 17;
      }
#pragma unroll
      for (int k = 0; k < 16; ++k) {
        float4* p = &hl4[dl16[k] * 32 + l];
        float4 t = *p;
        t.x += v[k].x; t.y += v[k].y; t.z += v[k].z; t.w += v[k].w;
        *p = t;
      }
    }
    ent = ent_next;
  }

  // Tail window (< 32 entries), 8-deep then scalar.
  {
    int base = nfull * 32;
    int m = c - base;
    int j = 0;
    for (; j + 8 <= m; j += 8) {
      float4 v[8];
      int dl8[8];
#pragma unroll
      for (int k = 0; k < 8; ++k) {
        int e = __shfl(ent, j + k, 32);
        v[k] = feat4[(size_t)(e & 0x1FFFF) * 32 + l];
        dl8[k] = e >> 17;
      }
#pragma unroll
      for (int k = 0; k < 8; ++k) {
        float4* p = &hl4[dl8[k] * 32 + l];
        float4 t = *p;
        t.x += v[k].x; t.y += v[k].y; t.z += v[k].z; t.w += v[k].w;
        *p = t;
      }
    }
    for (; j < m; ++j) {
      int e = __shfl(ent, j, 32);
      float4 v = feat4[(size_t)(e & 0x1FFFF) * 32 + l];
      float4* p = &hl4[(e >> 17) * 32 + l];
      float4 t = *p;
      t.x += v.x; t.y += v.y; t.z += v.z; t.w += v.w;
      *p = t;
    }
  }
  __syncthreads();

  // ---- Phase 2: out[64 x F] = relu(hl @ W + b) ----
  int cg = threadIdx.x & 31;   // column group (4 cols)
  int rg = threadIdx.x >> 5;   // row group base

  const float4* W4 = (const float4*)W;

  float4 bv = ((const float4*)b)[cg];
  float acc[8][4];
#pragma unroll
  for (int r = 0; r < 8; ++r) {
    acc[r][0] = bv.x; acc[r][1] = bv.y; acc[r][2] = bv.z; acc[r][3] = bv.w;
  }

#pragma unroll 2
  for (int d4 = 0; d4 < D / 4; ++d4) {
    float4 w0 = W4[(size_t)(4 * d4 + 0) * (F / 4) + cg];
    float4 w1 = W4[(size_t)(4 * d4 + 1) * (F / 4) + cg];
    float4 w2 = W4[(size_t)(4 * d4 + 2) * (F / 4) + cg];
    float4 w3 = W4[(size_t)(4 * d4 + 3) * (F / 4) + cg];
#pragma unroll
    for (int r = 0; r < 8; ++r) {
      float4 hv = hl4[(rg + 8 * r) * 32 + d4];
      acc[r][0] += hv.x * w0.x + hv.y * w1.x + hv.z * w2.x + hv.w * w3.x;
      acc[r][1] += hv.x * w0.y + hv.y * w1.y + hv.z * w2.y + hv.w * w3.y;
      acc[r][2] += hv.x * w0.z + hv.y * w1.z + hv.z * w2.z + hv.w * w3.z;
      acc[r][3] += hv.x * w0.w + hv.y * w1.w + hv.z * w2.w + hv.w * w3.w;
    }
  }

#pragma unroll
  for (int r = 0; r < 8; ++r) {
    int row = row0 + rg + 8 * r;
    if (row < N) {
      float4 o;
      o.x = fmaxf(acc[r][0], 0.f);
      o.y = fmaxf(acc[r][1], 0.f);
      o.z = fmaxf(acc[r][2], 0.f);
      o.w = fmaxf(acc[r][3], 0.f);
      ((float4*)out)[(size_t)row * (F / 4) + cg] = o;
    }
  }
}

// ---------------------------------------------------------------------------
extern "C" void kernel_launch(void* const* d_in, const int* in_sizes, int n_in,
                              void* d_out, int out_size, void* d_ws, size_t ws_size,
                              hipStream_t stream) {
  const float* feat = (const float*)d_in[0];   // [N, D]
  const float* W    = (const float*)d_in[1];   // [D, F]
  const float* b    = (const float*)d_in[2];   // [F]
  const int* src    = (const int*)d_in[3];     // [E]
  const int* dst    = (const int*)d_in[4];     // [E]

  int N = in_sizes[0] / D;
  int E = in_sizes[3];

  int nblocks = (N + 63) / 64;
  int nsub = nblocks * 8;

  // Workspace: bcnt [nsub*CPAD ints, line-padded] at 0 (~800KB);
  // bslot [nsub*SCAP ints] at 1MB (~12.8MB). Total ~13.8MB (ws >= 51.2MB).
  int* bcnt  = (int*)d_ws;
  int* bslot = (int*)((char*)d_ws + (1 << 20));

  float* out = (float*)d_out;

  hipMemsetAsync(bcnt, 0, (size_t)nsub * CPAD * sizeof(int), stream);

  fill_kernel<<<(E + 255) / 256, 256, 0, stream>>>(src, dst, bcnt, bslot, E);

  fused_kernel<<<nblocks, 256, 0, stream>>>(feat, bcnt, bslot, W, b, out, N);
}

// Round 5
// 305.052 us; speedup vs baseline: 1.1588x; 1.1588x over previous
//
#include <hip/hip_runtime.h>

// GCN layer: out = relu(segment_sum(features[edge_src], edge_dst) @ W + b)
// N=100000, E=1600000, D=F=128.
//
// Round-5 structure (round-4 post-mortem: per-edge GLOBAL atomics-with-return
// cost ~170us regardless of counter padding -> eliminate them entirely):
//  1) fill: 256 blocks, each owns a contiguous edge chunk. Bins edges by
//     bucket=dst>>6 via LDS counters into CHUNK-PRIVATE cells
//     slot[bucket][chunk][CAPC]. Zero global atomics, no memset needed.
//  2) fused: per dst-block of 64 rows: sweep the block's slot region
//     (contiguous, coalesced), bin entries by full row (64 LDS lists),
//     then accumulate each row in a REGISTER float4 (16-deep masked gather
//     batches; one LDS write per row), then register-tiled GEMM+bias+relu.

constexpr int D    = 128;  // input feature dim
constexpr int F    = 128;  // output feature dim
constexpr int NCH  = 256;  // edge chunks (= fill grid)
constexpr int CAPC = 24;   // per-(bucket,chunk) cell capacity; lambda=4
constexpr int ECAP = 44;   // per-row entry list capacity; lambda=16
constexpr int NBMAX = 2048; // max dst-blocks supported (N < 2^17)

// ---------------------------------------------------------------------------
// Kernel 1: chunk-private binning. Block c bins edges [c*CH,(c+1)*CH) by
// bucket=dst>>6 using LDS counters; entry = src | (dl<<17) (N<2^17).
// gcnt layout [chunk][bucket] (coalesced write); slot [bucket][chunk][CAPC]
// (contiguous per-bucket read in fused).
// ---------------------------------------------------------------------------
__global__ __launch_bounds__(256) void fill_kernel(
    const int* __restrict__ src,
    const int* __restrict__ dst,
    int* __restrict__ gcnt,
    int* __restrict__ gslot,
    int E, int NB, int CH) {
  __shared__ int lcnt[NBMAX];
  int c = blockIdx.x;

  for (int i = threadIdx.x; i < NB; i += 256) lcnt[i] = 0;
  __syncthreads();

  int e0 = c * CH;
  int e1 = min(E, e0 + CH);
  for (int e = e0 + threadIdx.x; e < e1; e += 256) {
    int t = dst[e];
    int s = src[e];
    int bucket = t >> 6;
    int entry = s | ((t & 63) << 17);
    int pos = atomicAdd(&lcnt[bucket], 1);   // LDS atomic
    if (pos < CAPC)
      gslot[((size_t)bucket * NCH + c) * CAPC + pos] = entry;
  }
  __syncthreads();

  for (int i = threadIdx.x; i < NB; i += 256)
    gcnt[(size_t)c * NB + i] = lcnt[i];
}

// ---------------------------------------------------------------------------
// Kernel 2 (fused): aggregate 64 rows + GEMM + bias + relu.
// ---------------------------------------------------------------------------
__global__ __launch_bounds__(256) void fused_kernel(
    const float* __restrict__ feat,
    const int* __restrict__ gcnt,
    const int* __restrict__ gslot,
    const float* __restrict__ W,
    const float* __restrict__ b,
    float* __restrict__ out,
    int N, int NB) {
  __shared__ float hl[64 * D];          // 32 KB
  __shared__ int ccnt[NCH];             // per-chunk counts for this bucket
  __shared__ int rcnt[64];              // per-row entry counts
  __shared__ int elist[64 * ECAP];      // per-row src lists (11 KB)

  int bb = blockIdx.x;                  // dst-block / bucket
  int tid = threadIdx.x;

  // ---- Stage 0: stage clamped per-chunk counts; zero row counters ----
  if (tid < NCH) ccnt[tid] = min(gcnt[(size_t)tid * NB + bb], CAPC);
  if (tid < 64) rcnt[tid] = 0;
  __syncthreads();

  // ---- Stage 1: sweep slot region (contiguous), bin by full row ----
  const int* sbase = gslot + (size_t)bb * NCH * CAPC;
  for (int i = tid; i < NCH * CAPC; i += 256) {
    int entry = sbase[i];
    int cell = i / CAPC;       // const divide -> magic mul
    int j = i - cell * CAPC;
    if (j < ccnt[cell]) {
      int row = (entry >> 17) & 63;
      int pos = atomicAdd(&rcnt[row], 1);   // LDS atomic, 64 addresses
      if (pos < ECAP) elist[row * ECAP + pos] = entry & 0x1FFFF;  // src only
    }
  }
  __syncthreads();

  // ---- Stage 2: per-row register accumulation ----
  // Group g (32 lanes) owns rows {g, g+8, ..., g+56}; lane l owns float4 l.
  int l = tid & 31;
  int g = tid >> 5;
  const float4* feat4 = (const float4*)feat;
  float4* hl4 = (float4*)hl;

  for (int r = 0; r < 8; ++r) {
    int row = g + 8 * r;
    int k = min(rcnt[row], ECAP);
    const int* el = &elist[row * ECAP];
    // stage up to 64 entries into 2 regs/lane (lanes >= k hold 0 -> row-0
    // dummy gathers, L1-hot, masked out of the accumulation)
    int ent0 = (l < k) ? el[l] : 0;
    int ent1 = (32 + l < k) ? el[32 + l] : 0;

    float4 a0 = make_float4(0.f, 0.f, 0.f, 0.f);
    float4 a1 = make_float4(0.f, 0.f, 0.f, 0.f);

    for (int j0 = 0; j0 < k; j0 += 16) {
      int ew = (j0 & 32) ? ent1 : ent0;
      int off = j0 & 16;
      float4 v[16];
#pragma unroll
      for (int t = 0; t < 16; ++t) {
        int s = __shfl(ew, off + t, 32);
        v[t] = feat4[(size_t)s * (D / 4) + l];
      }
#pragma unroll
      for (int t = 0; t < 16; ++t) {
        if (j0 + t < k) {
          if (t & 1) {
            a1.x += v[t].x; a1.y += v[t].y; a1.z += v[t].z; a1.w += v[t].w;
          } else {
            a0.x += v[t].x; a0.y += v[t].y; a0.z += v[t].z; a0.w += v[t].w;
          }
        }
      }
    }
    float4 a;
    a.x = a0.x + a1.x; a.y = a0.y + a1.y;
    a.z = a0.z + a1.z; a.w = a0.w + a1.w;
    hl4[row * (D / 4) + l] = a;          // single LDS write per row
  }
  __syncthreads();

  // ---- Stage 3: out[64 x F] = relu(hl @ W + b) ----
  int cg = tid & 31;   // column group (4 cols)
  int rg = tid >> 5;   // row group base
  int row0 = bb * 64;

  const float4* W4 = (const float4*)W;

  float4 bv = ((const float4*)b)[cg];
  float acc[8][4];
#pragma unroll
  for (int r = 0; r < 8; ++r) {
    acc[r][0] = bv.x; acc[r][1] = bv.y; acc[r][2] = bv.z; acc[r][3] = bv.w;
  }

#pragma unroll 2
  for (int d4 = 0; d4 < D / 4; ++d4) {
    float4 w0 = W4[(size_t)(4 * d4 + 0) * (F / 4) + cg];
    float4 w1 = W4[(size_t)(4 * d4 + 1) * (F / 4) + cg];
    float4 w2 = W4[(size_t)(4 * d4 + 2) * (F / 4) + cg];
    float4 w3 = W4[(size_t)(4 * d4 + 3) * (F / 4) + cg];
#pragma unroll
    for (int r = 0; r < 8; ++r) {
      float4 hv = hl4[(rg + 8 * r) * (D / 4) + d4];
      acc[r][0] += hv.x * w0.x + hv.y * w1.x + hv.z * w2.x + hv.w * w3.x;
      acc[r][1] += hv.x * w0.y + hv.y * w1.y + hv.z * w2.y + hv.w * w3.y;
      acc[r][2] += hv.x * w0.z + hv.y * w1.z + hv.z * w2.z + hv.w * w3.z;
      acc[r][3] += hv.x * w0.w + hv.y * w1.w + hv.z * w2.w + hv.w * w3.w;
    }
  }

#pragma unroll
  for (int r = 0; r < 8; ++r) {
    int row = row0 + rg + 8 * r;
    if (row < N) {
      float4 o;
      o.x = fmaxf(acc[r][0], 0.f);
      o.y = fmaxf(acc[r][1], 0.f);
      o.z = fmaxf(acc[r][2], 0.f);
      o.w = fmaxf(acc[r][3], 0.f);
      ((float4*)out)[(size_t)row * (F / 4) + cg] = o;
    }
  }
}

// ---------------------------------------------------------------------------
extern "C" void kernel_launch(void* const* d_in, const int* in_sizes, int n_in,
                              void* d_out, int out_size, void* d_ws, size_t ws_size,
                              hipStream_t stream) {
  const float* feat = (const float*)d_in[0];   // [N, D]
  const float* W    = (const float*)d_in[1];   // [D, F]
  const float* b    = (const float*)d_in[2];   // [F]
  const int* src    = (const int*)d_in[3];     // [E]
  const int* dst    = (const int*)d_in[4];     // [E]

  int N = in_sizes[0] / D;
  int E = in_sizes[3];

  int NB = (N + 63) / 64;                      // dst-blocks (1563)
  int CH = (E + NCH - 1) / NCH;                // edges per chunk (6250)

  // Workspace: gcnt [NCH*NB ints] at 0 (~1.6MB); slot [NB*NCH*CAPC ints]
  // at 2MB (~38.4MB). Total ~40.4MB (ws >= 51.2MB known from round 1).
  // No memset: fill writes every gcnt element; slot guarded by counts.
  int* gcnt  = (int*)d_ws;
  int* gslot = (int*)((char*)d_ws + (2u << 20));

  float* out = (float*)d_out;

  fill_kernel<<<NCH, 256, 0, stream>>>(src, dst, gcnt, gslot, E, NB, CH);

  fused_kernel<<<NB, 256, 0, stream>>>(feat, gcnt, gslot, W, b, out, N, NB);
}